// Round 1
// baseline (1350.641 us; speedup 1.0000x reference)
//
#include <hip/hip_runtime.h>

#define V   32768       // 32*32*32 coarse voxels
#define FV  262144      // 64^3 fine voxels

// ---------------------------------------------------------------------------
// Kernel A: y1[m][v] = bc[m] + sum_c Wc[m][c] * x[c][v]        (64 x V)
//           xp[v][oc] = sum_c Wp[oc][c] * x[c][v]              (V x 32, voxel-major)
// ---------------------------------------------------------------------------
__global__ __launch_bounds__(256) void kA(const float* __restrict__ x,
                                          const float* __restrict__ Wc,
                                          const float* __restrict__ bc,
                                          const float* __restrict__ Wp,
                                          float* __restrict__ y1,
                                          float* __restrict__ xp) {
    __shared__ float sWc[64 * 64];
    __shared__ float sbc[64];
    __shared__ float sWp[32 * 64];
    int tid = threadIdx.x;
    for (int i = tid; i < 64 * 64; i += 256) sWc[i] = Wc[i];
    for (int i = tid; i < 64; i += 256) sbc[i] = bc[i];
    for (int i = tid; i < 32 * 64; i += 256) sWp[i] = Wp[i];
    __syncthreads();

    int v = blockIdx.x * 256 + tid;
    float xv[64];
#pragma unroll
    for (int c = 0; c < 64; ++c) xv[c] = x[c * V + v];

    for (int m = 0; m < 64; ++m) {
        float acc = sbc[m];
#pragma unroll
        for (int c = 0; c < 64; ++c) acc += sWc[m * 64 + c] * xv[c];
        y1[m * V + v] = acc;
    }
    for (int oc = 0; oc < 32; ++oc) {
        float acc = 0.f;
#pragma unroll
        for (int c = 0; c < 64; ++c) acc += sWp[oc * 64 + c] * xv[c];
        xp[v * 32 + oc] = acc;
    }
}

// ---------------------------------------------------------------------------
// Kernel B: 3x3x3 conv, 64 -> 216 channels, zero padding 1.
// y2[o][z][h][w] = be[o] + sum_{c,dz,dy,dx} We[o][c][dz][dy][dx] *
//                                           y1[c][z+dz-1][h+dy-1][w+dx-1]
// blockIdx.x = z slice (32), blockIdx.y = output-channel group of 8 (27 groups)
// 256 threads: thread t covers voxels (h0 + 8q, w), h0 = t>>5, w = t&31, q=0..3
// ---------------------------------------------------------------------------
__global__ __launch_bounds__(256) void kB(const float* __restrict__ y1,
                                          const float* __restrict__ We,
                                          const float* __restrict__ be,
                                          float* __restrict__ y2) {
    __shared__ float sW[64 * 27 * 8];   // [(c*27+off)*8 + oo]
    int tid = threadIdx.x;
    int z = blockIdx.x, og = blockIdx.y;

    for (int idx = tid; idx < 64 * 27 * 8; idx += 256) {
        int oo = idx & 7;
        int rest = idx >> 3;
        int off = rest % 27;
        int c = rest / 27;
        sW[idx] = We[(og * 8 + oo) * 1728 + c * 27 + off];
    }
    __syncthreads();

    float acc[4][8];
#pragma unroll
    for (int oo = 0; oo < 8; ++oo) {
        float b = be[og * 8 + oo];
#pragma unroll
        for (int q = 0; q < 4; ++q) acc[q][oo] = b;
    }

    int h0 = tid >> 5;   // 0..7
    int w = tid & 31;

    for (int c = 0; c < 64; ++c) {
        const float* y1c = y1 + c * V;
#pragma unroll
        for (int dz = 0; dz < 3; ++dz) {
            int zz = z + dz - 1;
            bool zok = (zz >= 0 && zz < 32);
            int zc = zok ? zz : 0;
#pragma unroll
            for (int dy = 0; dy < 3; ++dy) {
#pragma unroll
                for (int dx = 0; dx < 3; ++dx) {
                    int xx = w + dx - 1;
                    bool xok = (xx >= 0 && xx < 32);
                    int xc = xok ? xx : 0;
                    float val[4];
#pragma unroll
                    for (int q = 0; q < 4; ++q) {
                        int hh = h0 + q * 8 + dy - 1;
                        bool hok = (hh >= 0 && hh < 32);
                        int hc = hok ? hh : 0;
                        float t = y1c[zc * 1024 + hc * 32 + xc];
                        val[q] = (zok && xok && hok) ? t : 0.f;
                    }
                    const float* wp = &sW[(c * 27 + dz * 9 + dy * 3 + dx) * 8];
#pragma unroll
                    for (int oo = 0; oo < 8; ++oo) {
                        float wv = wp[oo];
#pragma unroll
                        for (int q = 0; q < 4; ++q) acc[q][oo] += wv * val[q];
                    }
                }
            }
        }
    }

#pragma unroll
    for (int oo = 0; oo < 8; ++oo)
#pragma unroll
        for (int q = 0; q < 4; ++q)
            y2[(og * 8 + oo) * V + z * 1024 + (h0 + q * 8) * 32 + w] = acc[q][oo];
}

// ---------------------------------------------------------------------------
// Kernel C: pixel-shuffle + softmax(27) + CARAFE combine on xp + write out.
// blockIdx.x = d*32 + h. 256 threads: t -> (i = t>>7, j = (t>>6)&1, fx = t&63),
// fine voxel (2d+i, 2h+j, fx), source cell (d, h, w = fx>>1), sub l = fx&1.
// logits c: y2[(c*8 + i*4 + j*2 + l)][d][h][w]
// out[oc][fz][fy][fx] = sum_n softmax_n * xp[clamped neighbor][oc]
// ---------------------------------------------------------------------------
__global__ __launch_bounds__(256) void kC(const float* __restrict__ y2,
                                          const float* __restrict__ xp,
                                          float* __restrict__ out) {
    int bid = blockIdx.x;
    int d = bid >> 5, h = bid & 31;
    int t = threadIdx.x;
    int i = t >> 7, j = (t >> 6) & 1, fx = t & 63;
    int w = fx >> 1, l = fx & 1;
    int sub = i * 4 + j * 2 + l;
    int vc = d * 1024 + h * 32 + w;

    float lg[27];
#pragma unroll
    for (int c = 0; c < 27; ++c) lg[c] = y2[(c * 8 + sub) * V + vc];

    float m = lg[0];
#pragma unroll
    for (int c = 1; c < 27; ++c) m = fmaxf(m, lg[c]);
    float s = 0.f;
#pragma unroll
    for (int c = 0; c < 27; ++c) { lg[c] = expf(lg[c] - m); s += lg[c]; }
    float inv = 1.f / s;

    float acc[32];
#pragma unroll
    for (int oc = 0; oc < 32; ++oc) acc[oc] = 0.f;

#pragma unroll
    for (int dz = 0; dz < 3; ++dz) {
        int zz = min(max(d + dz - 1, 0), 31);
#pragma unroll
        for (int dy = 0; dy < 3; ++dy) {
            int yy = min(max(h + dy - 1, 0), 31);
#pragma unroll
            for (int dx = 0; dx < 3; ++dx) {
                int xx = min(max(w + dx - 1, 0), 31);
                float wn = lg[(dz * 3 + dy) * 3 + dx] * inv;
                const float4* p = (const float4*)(xp + (zz * 1024 + yy * 32 + xx) * 32);
#pragma unroll
                for (int q = 0; q < 8; ++q) {
                    float4 v4 = p[q];
                    acc[q * 4 + 0] += wn * v4.x;
                    acc[q * 4 + 1] += wn * v4.y;
                    acc[q * 4 + 2] += wn * v4.z;
                    acc[q * 4 + 3] += wn * v4.w;
                }
            }
        }
    }

    int fz = 2 * d + i, fy = 2 * h + j;
    int obase = fz * 4096 + fy * 64 + fx;
#pragma unroll
    for (int oc = 0; oc < 32; ++oc) out[oc * FV + obase] = acc[oc];
}

extern "C" void kernel_launch(void* const* d_in, const int* in_sizes, int n_in,
                              void* d_out, int out_size, void* d_ws, size_t ws_size,
                              hipStream_t stream) {
    const float* x  = (const float*)d_in[0];
    const float* Wc = (const float*)d_in[1];
    const float* bc = (const float*)d_in[2];
    const float* We = (const float*)d_in[3];
    const float* be = (const float*)d_in[4];
    const float* Wp = (const float*)d_in[5];
    float* out = (float*)d_out;

    float* ws = (float*)d_ws;
    float* y1 = ws;                          // 64 * 32768   = 2,097,152 floats
    float* xp = y1 + 64 * V;                 // 32768 * 32   = 1,048,576 floats
    float* y2 = xp + V * 32;                 // 216 * 32768  = 7,077,888 floats

    kA<<<V / 256, 256, 0, stream>>>(x, Wc, bc, Wp, y1, xp);
    kB<<<dim3(32, 27), 256, 0, stream>>>(y1, We, be, y2);
    kC<<<1024, 256, 0, stream>>>(y2, xp, out);
}

// Round 2
// 183.924 us; speedup vs baseline: 7.3435x; 7.3435x over previous
//
#include <hip/hip_runtime.h>
#include <hip/hip_bf16.h>

#define V   32768       // 32*32*32 coarse voxels
#define FV  262144      // 64^3 fine voxels

typedef __attribute__((ext_vector_type(8))) short bf16x8;
typedef __attribute__((ext_vector_type(4))) float f32x4;

__device__ __forceinline__ unsigned short f2bf(float f) {
    __hip_bfloat16 h = __float2bfloat16(f);   // RNE
    return __builtin_bit_cast(unsigned short, h);
}

__device__ __forceinline__ void gl_lds16(const void* g, void* l) {
    __builtin_amdgcn_global_load_lds(
        (const __attribute__((address_space(1))) unsigned int*)g,
        (__attribute__((address_space(3))) unsigned int*)l,
        16, 0, 0);
}

// ---------------------------------------------------------------------------
// Kernel A: y1[m][v] = bc[m] + sum_c Wc[m][c] * x[c][v]        (64 x V)
//           xp[v][oc] = sum_c Wp[oc][c] * x[c][v]              (V x 32)
// ---------------------------------------------------------------------------
__global__ __launch_bounds__(256) void kA(const float* __restrict__ x,
                                          const float* __restrict__ Wc,
                                          const float* __restrict__ bc,
                                          const float* __restrict__ Wp,
                                          float* __restrict__ y1,
                                          float* __restrict__ xp) {
    __shared__ float sWc[64 * 64];
    __shared__ float sbc[64];
    __shared__ float sWp[32 * 64];
    int tid = threadIdx.x;
    for (int i = tid; i < 64 * 64; i += 256) sWc[i] = Wc[i];
    for (int i = tid; i < 64; i += 256) sbc[i] = bc[i];
    for (int i = tid; i < 32 * 64; i += 256) sWp[i] = Wp[i];
    __syncthreads();

    int v = blockIdx.x * 256 + tid;
    float xv[64];
#pragma unroll
    for (int c = 0; c < 64; ++c) xv[c] = x[c * V + v];

    for (int m = 0; m < 64; ++m) {
        float acc = sbc[m];
#pragma unroll
        for (int c = 0; c < 64; ++c) acc += sWc[m * 64 + c] * xv[c];
        y1[m * V + v] = acc;
    }
    for (int oc = 0; oc < 32; ++oc) {
        float acc = 0.f;
#pragma unroll
        for (int c = 0; c < 64; ++c) acc += sWp[oc * 64 + c] * xv[c];
        xp[v * 32 + oc] = acc;
    }
}

// ---------------------------------------------------------------------------
// Kernel W: Ab[o][tap*64 + c] = bf16(We[o][c][tap]) ; 216 x 1728
// ---------------------------------------------------------------------------
__global__ __launch_bounds__(256) void kW(const float* __restrict__ We,
                                          unsigned short* __restrict__ Ab) {
    int idx = blockIdx.x * 256 + threadIdx.x;
    if (idx >= 216 * 1728) return;
    int o = idx / 1728, r = idx - o * 1728;
    int tap = r >> 6, c = r & 63;
    Ab[idx] = f2bf(We[(o * 64 + c) * 27 + tap]);
}

// ---------------------------------------------------------------------------
// Kernel I: im2col with zero padding, bf16.
// Bm[(v - vbase)][tap*64 + c] = bf16(y1[c][z+dz-1][h+dy-1][w+dx-1] or 0)
// One block per (z,h) row of 32 voxels. LDS stencil: sreg[c][dz*3+dy][x+1].
// ---------------------------------------------------------------------------
__global__ __launch_bounds__(256) void kI(const float* __restrict__ y1,
                                          unsigned short* __restrict__ Bm,
                                          int vbase) {
    __shared__ unsigned short sreg[64 * 9 * 34];   // 39168 B, zero-padded stencil
    int tid = threadIdx.x;
    int rowid = blockIdx.x + (vbase >> 5);         // global z*32+h
    int z = rowid >> 5, h = rowid & 31;

    for (int i = tid; i < 64 * 9 * 34; i += 256) sreg[i] = 0;
    __syncthreads();
    for (int i = tid; i < 64 * 288; i += 256) {
        int c = i / 288, rr = i - c * 288;
        int r9 = rr >> 5, xw = rr & 31;
        int dz = r9 / 3, dy = r9 - dz * 3;
        int zz = z + dz - 1, hh = h + dy - 1;
        if (zz >= 0 && zz < 32 && hh >= 0 && hh < 32)
            sreg[c * 306 + r9 * 34 + xw + 1] = f2bf(y1[c * V + zz * 1024 + hh * 32 + xw]);
    }
    __syncthreads();

    // 32 voxels * 216 16B-chunks per row; chunk ch covers k = 8ch..8ch+7
    // (fixed tap = ch>>3, c = (ch&7)*8 + j)
    for (int it = 0; it < 27; ++it) {
        int gci = it * 256 + tid;                  // 0..6911
        int w = gci / 216, ch = gci - w * 216;
        int tap = ch >> 3, c0 = (ch & 7) * 8;
        int dz = tap / 9, rem = tap - dz * 9;
        int dy = rem / 3, dx = rem - dy * 3;
        int base = (dz * 3 + dy) * 34 + w + dx;    // +1 pad -1 shift cancel
        unsigned int u[4];
#pragma unroll
        for (int p = 0; p < 4; ++p) {
            unsigned int lo = sreg[(c0 + 2 * p) * 306 + base];
            unsigned int hi = sreg[(c0 + 2 * p + 1) * 306 + base];
            u[p] = lo | (hi << 16);
        }
        uint4 val = make_uint4(u[0], u[1], u[2], u[3]);
        *(uint4*)(Bm + ((size_t)(blockIdx.x * 32 + w)) * 1728 + ch * 8) = val;
    }
}

// ---------------------------------------------------------------------------
// Kernel G: y2[m][n] = be[m] + sum_k Ab[m][k] * Bm[n][k]   (216 x vch x 1728)
// 128x128 tile, BK=64 (one tap), 4 waves (2x2), 16x16x32 bf16 MFMA.
// global_load_lds width 16 with XOR-swizzled source; swizzled ds_read_b128.
// blockIdx.y: m0 = 0 or 88 (rows 88..127 computed twice, identical values).
// ---------------------------------------------------------------------------
__global__ __launch_bounds__(256) void kG(const unsigned short* __restrict__ Ab,
                                          const unsigned short* __restrict__ Bm,
                                          const float* __restrict__ be,
                                          float* __restrict__ y2, int n_base) {
    __shared__ unsigned short sA[128 * 64];   // 16 KB, row-major [row][k], swizzled
    __shared__ unsigned short sB[128 * 64];
    int tid = threadIdx.x, lane = tid & 63, wid = tid >> 6;
    int m0 = blockIdx.y ? 88 : 0;
    int nloc = blockIdx.x * 128;

    f32x4 acc[4][4] = {};

    int wm = (wid >> 1) * 64;
    int wn = (wid & 1) * 64;

    // staging: wave wid owns rows wid*32..wid*32+31 (4 x 1KB instructions).
    // linear LDS slot (row, chunk) sources global chunk (chunk ^ (row&7)).
    int srow = wid * 32 + (lane >> 3);                    // + q*8
    int scol = ((lane & 7) ^ (lane >> 3)) * 8;            // swizzled 16B chunk (ushorts)
    const unsigned short* Asrc = Ab + (size_t)(m0 + srow) * 1728 + scol;
    const unsigned short* Bsrc = Bm + (size_t)(nloc + srow) * 1728 + scol;

    for (int kt = 0; kt < 27; ++kt) {
        __syncthreads();
#pragma unroll
        for (int q = 0; q < 4; ++q) {
            gl_lds16(Asrc + (size_t)q * 8 * 1728 + kt * 64, (char*)sA + (wid * 4 + q) * 1024);
            gl_lds16(Bsrc + (size_t)q * 8 * 1728 + kt * 64, (char*)sB + (wid * 4 + q) * 1024);
        }
        __syncthreads();
#pragma unroll
        for (int ks = 0; ks < 2; ++ks) {
            bf16x8 a[4], b[4];
#pragma unroll
            for (int i = 0; i < 4; ++i) {
                int ar = wm + i * 16 + (lane & 15);
                int ac = ((ks * 4 + (lane >> 4)) ^ (ar & 7)) * 8;
                a[i] = *(const bf16x8*)(sA + ar * 64 + ac);
                int br = wn + i * 16 + (lane & 15);
                int bc2 = ((ks * 4 + (lane >> 4)) ^ (br & 7)) * 8;
                b[i] = *(const bf16x8*)(sB + br * 64 + bc2);
            }
#pragma unroll
            for (int i = 0; i < 4; ++i)
#pragma unroll
                for (int j = 0; j < 4; ++j)
                    acc[i][j] = __builtin_amdgcn_mfma_f32_16x16x32_bf16(a[i], b[j], acc[i][j], 0, 0, 0);
        }
    }

    // C/D layout: col = lane&15, row = (lane>>4)*4 + reg
    int colb = n_base + nloc + wn + (lane & 15);
#pragma unroll
    for (int i = 0; i < 4; ++i) {
#pragma unroll
        for (int r = 0; r < 4; ++r) {
            int m = m0 + wm + i * 16 + (lane >> 4) * 4 + r;
            float bv = be[m];
#pragma unroll
            for (int j = 0; j < 4; ++j)
                y2[(size_t)m * V + colb + j * 16] = acc[i][j][r] + bv;
        }
    }
}

// ---------------------------------------------------------------------------
// Kernel C: pixel-shuffle + softmax(27) + CARAFE combine on xp + write out.
// ---------------------------------------------------------------------------
__global__ __launch_bounds__(256) void kC(const float* __restrict__ y2,
                                          const float* __restrict__ xp,
                                          float* __restrict__ out) {
    int bid = blockIdx.x;
    int d = bid >> 5, h = bid & 31;
    int t = threadIdx.x;
    int i = t >> 7, j = (t >> 6) & 1, fx = t & 63;
    int w = fx >> 1, l = fx & 1;
    int sub = i * 4 + j * 2 + l;
    int vc = d * 1024 + h * 32 + w;

    float lg[27];
#pragma unroll
    for (int c = 0; c < 27; ++c) lg[c] = y2[(c * 8 + sub) * V + vc];

    float m = lg[0];
#pragma unroll
    for (int c = 1; c < 27; ++c) m = fmaxf(m, lg[c]);
    float s = 0.f;
#pragma unroll
    for (int c = 0; c < 27; ++c) { lg[c] = expf(lg[c] - m); s += lg[c]; }
    float inv = 1.f / s;

    float acc[32];
#pragma unroll
    for (int oc = 0; oc < 32; ++oc) acc[oc] = 0.f;

#pragma unroll
    for (int dz = 0; dz < 3; ++dz) {
        int zz = min(max(d + dz - 1, 0), 31);
#pragma unroll
        for (int dy = 0; dy < 3; ++dy) {
            int yy = min(max(h + dy - 1, 0), 31);
#pragma unroll
            for (int dx = 0; dx < 3; ++dx) {
                int xx = min(max(w + dx - 1, 0), 31);
                float wn = lg[(dz * 3 + dy) * 3 + dx] * inv;
                const float4* p = (const float4*)(xp + (zz * 1024 + yy * 32 + xx) * 32);
#pragma unroll
                for (int q = 0; q < 8; ++q) {
                    float4 v4 = p[q];
                    acc[q * 4 + 0] += wn * v4.x;
                    acc[q * 4 + 1] += wn * v4.y;
                    acc[q * 4 + 2] += wn * v4.z;
                    acc[q * 4 + 3] += wn * v4.w;
                }
            }
        }
    }

    int fz = 2 * d + i, fy = 2 * h + j;
    int obase = fz * 4096 + fy * 64 + fx;
#pragma unroll
    for (int oc = 0; oc < 32; ++oc) out[oc * FV + obase] = acc[oc];
}

extern "C" void kernel_launch(void* const* d_in, const int* in_sizes, int n_in,
                              void* d_out, int out_size, void* d_ws, size_t ws_size,
                              hipStream_t stream) {
    const float* x  = (const float*)d_in[0];
    const float* Wc = (const float*)d_in[1];
    const float* bc = (const float*)d_in[2];
    const float* We = (const float*)d_in[3];
    const float* be = (const float*)d_in[4];
    const float* Wp = (const float*)d_in[5];
    float* out = (float*)d_out;

    float* ws = (float*)d_ws;
    float* y1 = ws;                                   // 64*V f32   =  8 MB
    float* xp = y1 + 64 * V;                          // 32*V f32   =  4 MB
    float* y2 = xp + 32 * V;                          // 216*V f32  = 28.3 MB
    unsigned short* Ab = (unsigned short*)(y2 + 216 * V);  // 216*1728 bf16
    unsigned short* Bm = Ab + 216 * 1728;             // im2col chunk, bf16

    // fit the im2col buffer into whatever workspace we actually have
    size_t fixed_bytes = (size_t)(64 + 32 + 216) * V * 4 + (size_t)216 * 1728 * 2;
    int nch = 1;
    while (nch < 16 && fixed_bytes + ((size_t)V / nch) * 1728 * 2 > ws_size) nch <<= 1;
    int vch = V / nch;

    kW<<<(216 * 1728 + 255) / 256, 256, 0, stream>>>(We, Ab);
    kA<<<V / 256, 256, 0, stream>>>(x, Wc, bc, Wp, y1, xp);
    for (int ci = 0; ci < nch; ++ci) {
        kI<<<vch / 32, 256, 0, stream>>>(y1, Bm, ci * vch);
        kG<<<dim3(vch / 128, 2), 256, 0, stream>>>(Ab, Bm, be, y2, ci * vch);
    }
    kC<<<1024, 256, 0, stream>>>(y2, xp, out);
}

// Round 3
// 141.940 us; speedup vs baseline: 9.5156x; 1.2958x over previous
//
#include <hip/hip_runtime.h>
#include <hip/hip_bf16.h>

#define V   32768       // 32*32*32 coarse voxels
#define FV  262144      // 64^3 fine voxels
#define PD  34          // padded dim
#define PP  1156        // 34*34
#define NP  39304       // 34^3

typedef __attribute__((ext_vector_type(8))) short bf16x8;
typedef __attribute__((ext_vector_type(4))) float f32x4;

__device__ __forceinline__ unsigned short f2bf(float f) {
    __hip_bfloat16 h = __float2bfloat16(f);   // RNE
    return __builtin_bit_cast(unsigned short, h);
}

__device__ __forceinline__ void gl_lds16(const void* g, void* l) {
    __builtin_amdgcn_global_load_lds(
        (const __attribute__((address_space(1))) unsigned int*)g,
        (__attribute__((address_space(3))) unsigned int*)l,
        16, 0, 0);
}

// ---------------------------------------------------------------------------
// Kernel Z: zero the padded y1p buffer (halo must be 0 every call).
// ---------------------------------------------------------------------------
__global__ __launch_bounds__(256) void kZ(uint4* __restrict__ p, int n16) {
    int i = blockIdx.x * 256 + threadIdx.x;
    if (i < n16) p[i] = make_uint4(0, 0, 0, 0);
}

// ---------------------------------------------------------------------------
// Kernel A: per-voxel 1x1x1 convs.
//   y1p[pad(v)][c] = bf16(bc[c] + sum_i Wc[c][i] * x[i][v])   (zero-haloed)
//   xp[v][oc]      = sum_i Wp[oc][i] * x[i][v]
// ---------------------------------------------------------------------------
__global__ __launch_bounds__(256) void kA(const float* __restrict__ x,
                                          const float* __restrict__ Wc,
                                          const float* __restrict__ bc,
                                          const float* __restrict__ Wp,
                                          unsigned short* __restrict__ y1p,
                                          float* __restrict__ xp) {
    __shared__ float sWc[64 * 64];
    __shared__ float sbc[64];
    __shared__ float sWp[32 * 64];
    int tid = threadIdx.x;
    for (int i = tid; i < 64 * 64; i += 256) sWc[i] = Wc[i];
    for (int i = tid; i < 64; i += 256) sbc[i] = bc[i];
    for (int i = tid; i < 32 * 64; i += 256) sWp[i] = Wp[i];
    __syncthreads();

    int v = blockIdx.x * 256 + tid;
    float xv[64];
#pragma unroll
    for (int c = 0; c < 64; ++c) xv[c] = x[c * V + v];

    // y1 row -> bf16 padded voxel-major
    int z = v >> 10, h = (v >> 5) & 31, w = v & 31;
    size_t pidx = (size_t)(z + 1) * PP + (h + 1) * PD + (w + 1);
    unsigned int row[32];
    for (int m = 0; m < 64; m += 2) {
        float a0 = sbc[m], a1 = sbc[m + 1];
#pragma unroll
        for (int c = 0; c < 64; ++c) {
            a0 += sWc[m * 64 + c] * xv[c];
            a1 += sWc[(m + 1) * 64 + c] * xv[c];
        }
        row[m >> 1] = (unsigned int)f2bf(a0) | ((unsigned int)f2bf(a1) << 16);
    }
#pragma unroll
    for (int q = 0; q < 8; ++q)
        *(uint4*)(y1p + pidx * 64 + q * 8) =
            make_uint4(row[q * 4], row[q * 4 + 1], row[q * 4 + 2], row[q * 4 + 3]);

    float pacc[32];
    for (int oc = 0; oc < 32; ++oc) {
        float acc = 0.f;
#pragma unroll
        for (int c = 0; c < 64; ++c) acc += sWp[oc * 64 + c] * xv[c];
        pacc[oc] = acc;
    }
#pragma unroll
    for (int q = 0; q < 8; ++q)
        *(float4*)(xp + (size_t)v * 32 + q * 4) =
            make_float4(pacc[q * 4], pacc[q * 4 + 1], pacc[q * 4 + 2], pacc[q * 4 + 3]);
}

// ---------------------------------------------------------------------------
// Kernel W: Ab[o][tap*64 + c] = bf16(We[o][c][tap]) ; 216 x 1728
// ---------------------------------------------------------------------------
__global__ __launch_bounds__(256) void kW(const float* __restrict__ We,
                                          unsigned short* __restrict__ Ab) {
    int idx = blockIdx.x * 256 + threadIdx.x;
    if (idx >= 216 * 1728) return;
    int o = idx / 1728, r = idx - o * 1728;
    int tap = r >> 6, c = r & 63;
    Ab[idx] = f2bf(We[(o * 64 + c) * 27 + tap]);
}

// ---------------------------------------------------------------------------
// Kernel G: implicit-GEMM 3x3x3 conv.
// y2[m][v] = be[m] + sum_{tap,c} Ab[m][tap*64+c] * y1p[pad(v)+toff(tap)][c]
// 128x128 tile, BK=64 (one tap per K-step), 4 waves (2x2), 16x16x32 bf16 MFMA.
// global_load_lds w16, XOR-swizzled source chunks, swizzled ds_read_b128.
// blockIdx.y: m0 = 0 or 88 (rows 88..127 computed twice, identical values).
// ---------------------------------------------------------------------------
__global__ __launch_bounds__(256) void kG(const unsigned short* __restrict__ Ab,
                                          const unsigned short* __restrict__ y1p,
                                          const float* __restrict__ be,
                                          float* __restrict__ y2) {
    __shared__ unsigned short sA[128 * 64];   // 16 KB, row-major [row][k], swizzled
    __shared__ unsigned short sB[128 * 64];
    int tid = threadIdx.x, lane = tid & 63, wid = tid >> 6;
    int m0 = blockIdx.y ? 88 : 0;
    int nloc = blockIdx.x * 128;

    f32x4 acc[4][4] = {};

    int wm = (wid >> 1) * 64;
    int wn = (wid & 1) * 64;

    // staging: wave wid owns rows wid*32..wid*32+31 (4 x 1KB instructions).
    // linear LDS slot (row, chunk) sources global chunk (chunk ^ (row&7)).
    int srow = wid * 32 + (lane >> 3);                    // + q*8
    int scol = ((lane & 7) ^ (lane >> 3)) * 8;            // swizzled 16B chunk (ushorts)
    const unsigned short* Asrc = Ab + (size_t)(m0 + srow) * 1728 + scol;

    // B: per-lane padded-voxel base for each of its 4 staged rows
    const unsigned short* Bsrc[4];
#pragma unroll
    for (int q = 0; q < 4; ++q) {
        int v = nloc + srow + q * 8;
        int z = v >> 10, h = (v >> 5) & 31, w = v & 31;
        size_t pidx = (size_t)(z + 1) * PP + (h + 1) * PD + (w + 1);
        Bsrc[q] = y1p + pidx * 64 + scol;
    }

    for (int kt = 0; kt < 27; ++kt) {
        int dz = kt / 9, rem = kt - dz * 9;
        int dy = rem / 3, dx = rem - dy * 3;
        int toff = ((dz - 1) * PP + (dy - 1) * PD + (dx - 1)) * 64;
        __syncthreads();
#pragma unroll
        for (int q = 0; q < 4; ++q) {
            gl_lds16(Asrc + (size_t)q * 8 * 1728 + kt * 64, (char*)sA + (wid * 4 + q) * 1024);
            gl_lds16(Bsrc[q] + toff, (char*)sB + (wid * 4 + q) * 1024);
        }
        __syncthreads();
#pragma unroll
        for (int ks = 0; ks < 2; ++ks) {
            bf16x8 a[4], b[4];
#pragma unroll
            for (int i = 0; i < 4; ++i) {
                int ar = wm + i * 16 + (lane & 15);
                int ac = ((ks * 4 + (lane >> 4)) ^ (ar & 7)) * 8;
                a[i] = *(const bf16x8*)(sA + ar * 64 + ac);
                int br = wn + i * 16 + (lane & 15);
                int bc2 = ((ks * 4 + (lane >> 4)) ^ (br & 7)) * 8;
                b[i] = *(const bf16x8*)(sB + br * 64 + bc2);
            }
#pragma unroll
            for (int i = 0; i < 4; ++i)
#pragma unroll
                for (int j = 0; j < 4; ++j)
                    acc[i][j] = __builtin_amdgcn_mfma_f32_16x16x32_bf16(a[i], b[j], acc[i][j], 0, 0, 0);
        }
    }

    // C/D layout: col = lane&15, row = (lane>>4)*4 + reg
    int colb = nloc + wn + (lane & 15);
#pragma unroll
    for (int i = 0; i < 4; ++i) {
#pragma unroll
        for (int r = 0; r < 4; ++r) {
            int m = m0 + wm + i * 16 + (lane >> 4) * 4 + r;
            float bv = be[m];
#pragma unroll
            for (int j = 0; j < 4; ++j)
                y2[(size_t)m * V + colb + j * 16] = acc[i][j][r] + bv;
        }
    }
}

// ---------------------------------------------------------------------------
// Kernel C: pixel-shuffle + softmax(27) + CARAFE combine on xp + write out.
// grid 2048: blockIdx.x = (d*32 + h)*2 + ocg; each block does 16 out-channels.
// ---------------------------------------------------------------------------
__global__ __launch_bounds__(256) void kC(const float* __restrict__ y2,
                                          const float* __restrict__ xp,
                                          float* __restrict__ out) {
    int bid = blockIdx.x;
    int ocg = bid & 1;
    int cell = bid >> 1;
    int d = cell >> 5, h = cell & 31;
    int t = threadIdx.x;
    int i = t >> 7, j = (t >> 6) & 1, fx = t & 63;
    int w = fx >> 1, l = fx & 1;
    int sub = i * 4 + j * 2 + l;
    int vc = d * 1024 + h * 32 + w;

    float lg[27];
#pragma unroll
    for (int c = 0; c < 27; ++c) lg[c] = y2[(c * 8 + sub) * V + vc];

    float m = lg[0];
#pragma unroll
    for (int c = 1; c < 27; ++c) m = fmaxf(m, lg[c]);
    float s = 0.f;
#pragma unroll
    for (int c = 0; c < 27; ++c) { lg[c] = expf(lg[c] - m); s += lg[c]; }
    float inv = 1.f / s;

    float acc[16];
#pragma unroll
    for (int oc = 0; oc < 16; ++oc) acc[oc] = 0.f;

#pragma unroll
    for (int dz = 0; dz < 3; ++dz) {
        int zz = min(max(d + dz - 1, 0), 31);
#pragma unroll
        for (int dy = 0; dy < 3; ++dy) {
            int yy = min(max(h + dy - 1, 0), 31);
#pragma unroll
            for (int dx = 0; dx < 3; ++dx) {
                int xx = min(max(w + dx - 1, 0), 31);
                float wn = lg[(dz * 3 + dy) * 3 + dx] * inv;
                const float4* p = (const float4*)(xp + (size_t)(zz * 1024 + yy * 32 + xx) * 32) + ocg * 4;
#pragma unroll
                for (int q = 0; q < 4; ++q) {
                    float4 v4 = p[q];
                    acc[q * 4 + 0] += wn * v4.x;
                    acc[q * 4 + 1] += wn * v4.y;
                    acc[q * 4 + 2] += wn * v4.z;
                    acc[q * 4 + 3] += wn * v4.w;
                }
            }
        }
    }

    int fz = 2 * d + i, fy = 2 * h + j;
    size_t obase = (size_t)(ocg * 16) * FV + fz * 4096 + fy * 64 + fx;
#pragma unroll
    for (int oc = 0; oc < 16; ++oc) out[obase + (size_t)oc * FV] = acc[oc];
}

extern "C" void kernel_launch(void* const* d_in, const int* in_sizes, int n_in,
                              void* d_out, int out_size, void* d_ws, size_t ws_size,
                              hipStream_t stream) {
    const float* x  = (const float*)d_in[0];
    const float* Wc = (const float*)d_in[1];
    const float* bc = (const float*)d_in[2];
    const float* We = (const float*)d_in[3];
    const float* be = (const float*)d_in[4];
    const float* Wp = (const float*)d_in[5];
    float* out = (float*)d_out;

    float* ws = (float*)d_ws;
    float* y2 = ws;                                        // 216*V f32 = 28.3 MB
    float* xp = y2 + (size_t)216 * V;                      // 32*V  f32 =  4 MB
    unsigned short* Ab  = (unsigned short*)(xp + (size_t)32 * V);  // 216*1728 bf16
    unsigned short* y1p = Ab + (size_t)216 * 1728;         // 34^3*64 bf16 = 5 MB

    int n16 = (NP * 64) / 8;   // uint4 count of y1p
    kZ<<<(n16 + 255) / 256, 256, 0, stream>>>((uint4*)y1p, n16);
    kW<<<(216 * 1728 + 255) / 256, 256, 0, stream>>>(We, Ab);
    kA<<<V / 256, 256, 0, stream>>>(x, Wc, bc, Wp, y1p, xp);
    kG<<<dim3(V / 128, 2), 256, 0, stream>>>(Ab, y1p, be, y2);
    kC<<<2048, 256, 0, stream>>>(y2, xp, out);
}

// Round 4
// 103.989 us; speedup vs baseline: 12.9883x; 1.3649x over previous
//
#include <hip/hip_runtime.h>
#include <hip/hip_bf16.h>

#define V   32768       // 32*32*32 coarse voxels
#define FV  262144      // 64^3 fine voxels
#define PD  34          // padded dim
#define PP  1156        // 34*34
#define NP  39304       // 34^3

typedef __attribute__((ext_vector_type(8))) short bf16x8;
typedef __attribute__((ext_vector_type(4))) float f32x4;

__device__ __forceinline__ unsigned short f2bf(float f) {
    __hip_bfloat16 h = __float2bfloat16(f);   // RNE
    return __builtin_bit_cast(unsigned short, h);
}

__device__ __forceinline__ void gl_lds16(const void* g, void* l) {
    __builtin_amdgcn_global_load_lds(
        (const __attribute__((address_space(1))) unsigned int*)g,
        (__attribute__((address_space(3))) unsigned int*)l,
        16, 0, 0);
}

// ---------------------------------------------------------------------------
// Kernel Z: zero the padded y1p buffer (halo must be 0 every call).
// ---------------------------------------------------------------------------
__global__ __launch_bounds__(256) void kZ(uint4* __restrict__ p, int n16) {
    int i = blockIdx.x * 256 + threadIdx.x;
    if (i < n16) p[i] = make_uint4(0, 0, 0, 0);
}

// ---------------------------------------------------------------------------
// Kernel A: per-voxel 1x1x1 convs.
//   y1p[pad(v)][c] = bf16(bc[c] + sum_i Wc[c][i] * x[i][v])   (zero-haloed)
//   xp[v][oc]      = sum_i Wp[oc][i] * x[i][v]
// ---------------------------------------------------------------------------
__global__ __launch_bounds__(256) void kA(const float* __restrict__ x,
                                          const float* __restrict__ Wc,
                                          const float* __restrict__ bc,
                                          const float* __restrict__ Wp,
                                          unsigned short* __restrict__ y1p,
                                          float* __restrict__ xp) {
    __shared__ float sWc[64 * 64];
    __shared__ float sbc[64];
    __shared__ float sWp[32 * 64];
    int tid = threadIdx.x;
    for (int i = tid; i < 64 * 64; i += 256) sWc[i] = Wc[i];
    for (int i = tid; i < 64; i += 256) sbc[i] = bc[i];
    for (int i = tid; i < 32 * 64; i += 256) sWp[i] = Wp[i];
    __syncthreads();

    int v = blockIdx.x * 256 + tid;
    float xv[64];
#pragma unroll
    for (int c = 0; c < 64; ++c) xv[c] = x[c * V + v];

    // y1 row -> bf16 padded voxel-major
    int z = v >> 10, h = (v >> 5) & 31, w = v & 31;
    size_t pidx = (size_t)(z + 1) * PP + (h + 1) * PD + (w + 1);
    unsigned int row[32];
    for (int m = 0; m < 64; m += 2) {
        float a0 = sbc[m], a1 = sbc[m + 1];
#pragma unroll
        for (int c = 0; c < 64; ++c) {
            a0 += sWc[m * 64 + c] * xv[c];
            a1 += sWc[(m + 1) * 64 + c] * xv[c];
        }
        row[m >> 1] = (unsigned int)f2bf(a0) | ((unsigned int)f2bf(a1) << 16);
    }
#pragma unroll
    for (int q = 0; q < 8; ++q)
        *(uint4*)(y1p + pidx * 64 + q * 8) =
            make_uint4(row[q * 4], row[q * 4 + 1], row[q * 4 + 2], row[q * 4 + 3]);

    float pacc[32];
    for (int oc = 0; oc < 32; ++oc) {
        float acc = 0.f;
#pragma unroll
        for (int c = 0; c < 64; ++c) acc += sWp[oc * 64 + c] * xv[c];
        pacc[oc] = acc;
    }
#pragma unroll
    for (int q = 0; q < 8; ++q)
        *(float4*)(xp + (size_t)v * 32 + q * 4) =
            make_float4(pacc[q * 4], pacc[q * 4 + 1], pacc[q * 4 + 2], pacc[q * 4 + 3]);
}

// ---------------------------------------------------------------------------
// Kernel W: Ab[o][tap*64 + c] = bf16(We[o][c][tap]) ; 216 x 1728
// ---------------------------------------------------------------------------
__global__ __launch_bounds__(256) void kW(const float* __restrict__ We,
                                          unsigned short* __restrict__ Ab) {
    int idx = blockIdx.x * 256 + threadIdx.x;
    if (idx >= 216 * 1728) return;
    int o = idx / 1728, r = idx - o * 1728;
    int tap = r >> 6, c = r & 63;
    Ab[idx] = f2bf(We[(o * 64 + c) * 27 + tap]);
}

// ---------------------------------------------------------------------------
// Kernel G: implicit-GEMM 3x3x3 conv.
// y2[m][v] = be[m] + sum_{tap,c} Ab[m][tap*64+c] * y1p[pad(v)+toff(tap)][c]
// 128x128 tile, BK=64 (one tap per K-step), 4 waves (2x2), 16x16x32 bf16 MFMA.
// ---------------------------------------------------------------------------
__global__ __launch_bounds__(256) void kG(const unsigned short* __restrict__ Ab,
                                          const unsigned short* __restrict__ y1p,
                                          const float* __restrict__ be,
                                          float* __restrict__ y2) {
    __shared__ unsigned short sA[128 * 64];   // 16 KB, row-major [row][k], swizzled
    __shared__ unsigned short sB[128 * 64];
    int tid = threadIdx.x, lane = tid & 63, wid = tid >> 6;
    int m0 = blockIdx.y ? 88 : 0;
    int nloc = blockIdx.x * 128;

    f32x4 acc[4][4] = {};

    int wm = (wid >> 1) * 64;
    int wn = (wid & 1) * 64;

    // staging: wave wid owns rows wid*32..wid*32+31 (4 x 1KB instructions).
    // linear LDS slot (row, chunk) sources global chunk (chunk ^ (row&7)).
    int srow = wid * 32 + (lane >> 3);                    // + q*8
    int scol = ((lane & 7) ^ (lane >> 3)) * 8;            // swizzled 16B chunk (ushorts)
    const unsigned short* Asrc = Ab + (size_t)(m0 + srow) * 1728 + scol;

    // B: per-lane padded-voxel base for each of its 4 staged rows
    const unsigned short* Bsrc[4];
#pragma unroll
    for (int q = 0; q < 4; ++q) {
        int v = nloc + srow + q * 8;
        int z = v >> 10, h = (v >> 5) & 31, w = v & 31;
        size_t pidx = (size_t)(z + 1) * PP + (h + 1) * PD + (w + 1);
        Bsrc[q] = y1p + pidx * 64 + scol;
    }

    for (int kt = 0; kt < 27; ++kt) {
        int dz = kt / 9, rem = kt - dz * 9;
        int dy = rem / 3, dx = rem - dy * 3;
        int toff = ((dz - 1) * PP + (dy - 1) * PD + (dx - 1)) * 64;
        __syncthreads();
#pragma unroll
        for (int q = 0; q < 4; ++q) {
            gl_lds16(Asrc + (size_t)q * 8 * 1728 + kt * 64, (char*)sA + (wid * 4 + q) * 1024);
            gl_lds16(Bsrc[q] + toff, (char*)sB + (wid * 4 + q) * 1024);
        }
        __syncthreads();
#pragma unroll
        for (int ks = 0; ks < 2; ++ks) {
            bf16x8 a[4], b[4];
#pragma unroll
            for (int i = 0; i < 4; ++i) {
                int ar = wm + i * 16 + (lane & 15);
                int ac = ((ks * 4 + (lane >> 4)) ^ (ar & 7)) * 8;
                a[i] = *(const bf16x8*)(sA + ar * 64 + ac);
                int br = wn + i * 16 + (lane & 15);
                int bc2 = ((ks * 4 + (lane >> 4)) ^ (br & 7)) * 8;
                b[i] = *(const bf16x8*)(sB + br * 64 + bc2);
            }
#pragma unroll
            for (int i = 0; i < 4; ++i)
#pragma unroll
                for (int j = 0; j < 4; ++j)
                    acc[i][j] = __builtin_amdgcn_mfma_f32_16x16x32_bf16(a[i], b[j], acc[i][j], 0, 0, 0);
        }
    }

    // C/D layout: col = lane&15, row = (lane>>4)*4 + reg
    int colb = nloc + wn + (lane & 15);
#pragma unroll
    for (int i = 0; i < 4; ++i) {
#pragma unroll
        for (int r = 0; r < 4; ++r) {
            int m = m0 + wm + i * 16 + (lane >> 4) * 4 + r;
            float bv = be[m];
#pragma unroll
            for (int j = 0; j < 4; ++j)
                y2[(size_t)m * V + colb + j * 16] = acc[i][j][r] + bv;
        }
    }
}

// ---------------------------------------------------------------------------
// Kernel C: pixel-shuffle + softmax(27) + CARAFE combine, LDS-staged.
// Block = one (d,h) cell-row (1024 blocks, 256 threads).
// Phase 1: stage logits slog[sub][tap][w] + xp rows sxp[zy][xx][chunk-XOR].
// Phase 2: thread (g = t>>5, w = t&31) does softmax for sub=g, cell w
//          (in place -- touches only its own slots).
// Phase 3: thread (g, w) = channels g*4..g*4+3, all 8 subs, cell w.
//          Per tap: 1 swizzled b128 xp read (reused by 8 subs) + 8 bcast b32.
// ---------------------------------------------------------------------------
__global__ __launch_bounds__(256) void kC(const float* __restrict__ y2,
                                          const float* __restrict__ xp,
                                          float* __restrict__ out) {
    __shared__ float  slog[8][27][32];   // 27.6 KB
    __shared__ float4 sxp[9][32][8];     // 36.9 KB
    int t = threadIdx.x;
    int bid = blockIdx.x;
    int d = bid >> 5, h = bid & 31;
    int g = t >> 5, w = t & 31;

    // phase 1a: logits (coalesced 128B segments)
    int vc = d * 1024 + h * 32 + w;
#pragma unroll
    for (int it = 0; it < 27; ++it)
        slog[g][it][w] = y2[(size_t)(it * 8 + g) * V + vc];

    // phase 1b: xp neighborhood rows (fully coalesced float4)
    {
        int xx = t >> 3, q = t & 7;
#pragma unroll
        for (int zy = 0; zy < 9; ++zy) {
            int zi = zy / 3, yi = zy - zi * 3;
            int zz = min(max(d + zi - 1, 0), 31);
            int yy = min(max(h + yi - 1, 0), 31);
            float4 v4 = *(const float4*)(xp + (size_t)(zz * 1024 + yy * 32 + xx) * 32 + q * 4);
            sxp[zy][xx][q ^ (xx & 7)] = v4;
        }
    }
    __syncthreads();

    // phase 2: softmax over 27 taps for (sub=g, cell w), in place
    {
        float lg[27];
#pragma unroll
        for (int tp = 0; tp < 27; ++tp) lg[tp] = slog[g][tp][w];
        float m = lg[0];
#pragma unroll
        for (int tp = 1; tp < 27; ++tp) m = fmaxf(m, lg[tp]);
        float s = 0.f;
#pragma unroll
        for (int tp = 0; tp < 27; ++tp) { lg[tp] = __expf(lg[tp] - m); s += lg[tp]; }
        float inv = 1.f / s;
#pragma unroll
        for (int tp = 0; tp < 27; ++tp) slog[g][tp][w] = lg[tp] * inv;
    }
    __syncthreads();

    // phase 3: combine
    float acc[8][4] = {};
#pragma unroll
    for (int zy = 0; zy < 9; ++zy) {
#pragma unroll
        for (int dx = 0; dx < 3; ++dx) {
            int tap = zy * 3 + dx;
            int xx = min(max(w + dx - 1, 0), 31);
            float4 xv = sxp[zy][xx][g ^ (xx & 7)];
            float wn[8];
#pragma unroll
            for (int sub = 0; sub < 8; ++sub) wn[sub] = slog[sub][tap][w];
#pragma unroll
            for (int sub = 0; sub < 8; ++sub) {
                acc[sub][0] += wn[sub] * xv.x;
                acc[sub][1] += wn[sub] * xv.y;
                acc[sub][2] += wn[sub] * xv.z;
                acc[sub][3] += wn[sub] * xv.w;
            }
        }
    }

    // epilogue: pair l=0/1 into float2 (fx = 2w, 2w+1)
    int fzb = 2 * d, fyb = 2 * h;
#pragma unroll
    for (int sp = 0; sp < 4; ++sp) {          // sub pair (2sp, 2sp+1), sp = i*2+j
        int i = sp >> 1, j = sp & 1;
        size_t ob = (size_t)(fzb + i) * 4096 + (size_t)(fyb + j) * 64 + 2 * w;
#pragma unroll
        for (int k = 0; k < 4; ++k) {
            float2 v2 = make_float2(acc[2 * sp][k], acc[2 * sp + 1][k]);
            *(float2*)(out + (size_t)(g * 4 + k) * FV + ob) = v2;
        }
    }
}

extern "C" void kernel_launch(void* const* d_in, const int* in_sizes, int n_in,
                              void* d_out, int out_size, void* d_ws, size_t ws_size,
                              hipStream_t stream) {
    const float* x  = (const float*)d_in[0];
    const float* Wc = (const float*)d_in[1];
    const float* bc = (const float*)d_in[2];
    const float* We = (const float*)d_in[3];
    const float* be = (const float*)d_in[4];
    const float* Wp = (const float*)d_in[5];
    float* out = (float*)d_out;

    float* ws = (float*)d_ws;
    float* y2 = ws;                                        // 216*V f32 = 28.3 MB
    float* xp = y2 + (size_t)216 * V;                      // 32*V  f32 =  4 MB
    unsigned short* Ab  = (unsigned short*)(xp + (size_t)32 * V);  // 216*1728 bf16
    unsigned short* y1p = Ab + (size_t)216 * 1728;         // 34^3*64 bf16 = 5 MB

    int n16 = (NP * 64) / 8;   // uint4 count of y1p
    kZ<<<(n16 + 255) / 256, 256, 0, stream>>>((uint4*)y1p, n16);
    kW<<<(216 * 1728 + 255) / 256, 256, 0, stream>>>(We, Ab);
    kA<<<V / 256, 256, 0, stream>>>(x, Wc, bc, Wp, y1p, xp);
    kG<<<dim3(V / 128, 2), 256, 0, stream>>>(Ab, y1p, be, y2);
    kC<<<1024, 256, 0, stream>>>(y2, xp, out);
}

// Round 5
// 102.580 us; speedup vs baseline: 13.1668x; 1.0137x over previous
//
#include <hip/hip_runtime.h>
#include <hip/hip_bf16.h>

#define V   32768       // 32*32*32 coarse voxels
#define FV  262144      // 64^3 fine voxels
#define PD  34          // padded dim
#define PP  1156        // 34*34
#define NP  39304       // 34^3

#define NBA 154         // y1p role blocks (ceil(NP/256))
#define NBX 128         // xp role blocks  (V/256)
#define NBW 1458        // weight-permute role blocks (216*1728/256)

typedef __attribute__((ext_vector_type(8))) short bf16x8;
typedef __attribute__((ext_vector_type(4))) float f32x4;

__device__ __forceinline__ unsigned short f2bf(float f) {
    __hip_bfloat16 h = __float2bfloat16(f);   // RNE
    return __builtin_bit_cast(unsigned short, h);
}

__device__ __forceinline__ void gl_lds16(const void* g, void* l) {
    __builtin_amdgcn_global_load_lds(
        (const __attribute__((address_space(1))) unsigned int*)g,
        (__attribute__((address_space(3))) unsigned int*)l,
        16, 0, 0);
}

// ---------------------------------------------------------------------------
// Kernel P (fused prep), role by blockIdx.x:
//  [0,NBA):        y1p[p][c] = bf16(bc[c] + Wc.x[v(p)])  over PADDED voxels,
//                  halo rows written as zeros (kills the kZ pre-pass).
//  [NBA,NBA+NBX):  xp[v][oc] = Wp.x[v]                    (f32, voxel-major)
//  [NBA+NBX, ...): Ab[o][tap*64+c] = bf16(We[o][c][tap])  (GEMM A permute)
// Weights read from LDS as float4 broadcasts (ds_read_b128).
// ---------------------------------------------------------------------------
__global__ __launch_bounds__(256) void kP(const float* __restrict__ x,
                                          const float* __restrict__ Wc,
                                          const float* __restrict__ bc,
                                          const float* __restrict__ Wp,
                                          const float* __restrict__ We,
                                          unsigned short* __restrict__ y1p,
                                          float* __restrict__ xp,
                                          unsigned short* __restrict__ Ab) {
    __shared__ __align__(16) float sw[64 * 64];
    __shared__ float sbc[64];
    int tid = threadIdx.x;
    int bid = blockIdx.x;

    if (bid < NBA) {
        // ---- y1p role ----
        for (int i = tid; i < 64 * 64; i += 256) sw[i] = Wc[i];
        for (int i = tid; i < 64; i += 256) sbc[i] = bc[i];
        __syncthreads();

        int p = bid * 256 + tid;
        if (p >= NP) return;
        int pz = p / PP, rr = p - pz * PP;
        int py = rr / PD, px = rr - py * PD;
        unsigned short* dst = y1p + (size_t)p * 64;

        if (pz == 0 || pz == 33 || py == 0 || py == 33 || px == 0 || px == 33) {
            uint4 z4 = make_uint4(0, 0, 0, 0);
#pragma unroll
            for (int q = 0; q < 8; ++q) *(uint4*)(dst + q * 8) = z4;
            return;
        }
        int v = (pz - 1) * 1024 + (py - 1) * 32 + (px - 1);
        float xv[64];
#pragma unroll
        for (int c = 0; c < 64; ++c) xv[c] = x[c * V + v];

        unsigned int row[32];
        for (int m = 0; m < 64; m += 2) {
            float a0 = sbc[m], a1 = sbc[m + 1];
#pragma unroll
            for (int c4 = 0; c4 < 16; ++c4) {
                float4 w0 = *(const float4*)(sw + m * 64 + c4 * 4);
                float4 w1 = *(const float4*)(sw + (m + 1) * 64 + c4 * 4);
                a0 += w0.x * xv[c4 * 4] + w0.y * xv[c4 * 4 + 1] +
                      w0.z * xv[c4 * 4 + 2] + w0.w * xv[c4 * 4 + 3];
                a1 += w1.x * xv[c4 * 4] + w1.y * xv[c4 * 4 + 1] +
                      w1.z * xv[c4 * 4 + 2] + w1.w * xv[c4 * 4 + 3];
            }
            row[m >> 1] = (unsigned int)f2bf(a0) | ((unsigned int)f2bf(a1) << 16);
        }
#pragma unroll
        for (int q = 0; q < 8; ++q)
            *(uint4*)(dst + q * 8) =
                make_uint4(row[q * 4], row[q * 4 + 1], row[q * 4 + 2], row[q * 4 + 3]);

    } else if (bid < NBA + NBX) {
        // ---- xp role ----
        for (int i = tid; i < 32 * 64; i += 256) sw[i] = Wp[i];
        __syncthreads();

        int v = (bid - NBA) * 256 + tid;
        float xv[64];
#pragma unroll
        for (int c = 0; c < 64; ++c) xv[c] = x[c * V + v];

        float pacc[32];
        for (int oc = 0; oc < 32; ++oc) {
            float acc = 0.f;
#pragma unroll
            for (int c4 = 0; c4 < 16; ++c4) {
                float4 w0 = *(const float4*)(sw + oc * 64 + c4 * 4);
                acc += w0.x * xv[c4 * 4] + w0.y * xv[c4 * 4 + 1] +
                       w0.z * xv[c4 * 4 + 2] + w0.w * xv[c4 * 4 + 3];
            }
            pacc[oc] = acc;
        }
#pragma unroll
        for (int q = 0; q < 8; ++q)
            *(float4*)(xp + (size_t)v * 32 + q * 4) =
                make_float4(pacc[q * 4], pacc[q * 4 + 1], pacc[q * 4 + 2], pacc[q * 4 + 3]);

    } else {
        // ---- weight permute role ----
        int idx = (bid - NBA - NBX) * 256 + tid;
        int o = idx / 1728, r = idx - o * 1728;
        int tap = r >> 6, c = r & 63;
        Ab[idx] = f2bf(We[(o * 64 + c) * 27 + tap]);
    }
}

// ---------------------------------------------------------------------------
// Kernel G: implicit-GEMM 3x3x3 conv, double-buffered (T3-min 2-phase).
// y2[m][v] = be[m] + sum_{tap,c} Ab[m][tap*64+c] * y1p[pad(v)+toff(tap)][c]
// 128x128 tile, BK=64 (one tap per K-step), 4 waves (2x2), 16x16x32 bf16 MFMA.
// Prefetch of tap kt+1 is issued BEFORE compute of tap kt (loads fly under
// ds_read+MFMA); one barrier per tap.
// ---------------------------------------------------------------------------
__global__ __launch_bounds__(256) void kG(const unsigned short* __restrict__ Ab,
                                          const unsigned short* __restrict__ y1p,
                                          const float* __restrict__ be,
                                          float* __restrict__ y2) {
    __shared__ unsigned short sA[2][128 * 64];   // 2 x 16 KB, swizzled chunks
    __shared__ unsigned short sB[2][128 * 64];
    int tid = threadIdx.x, lane = tid & 63, wid = tid >> 6;
    int m0 = blockIdx.y ? 88 : 0;
    int nloc = blockIdx.x * 128;

    f32x4 acc[4][4] = {};

    int wm = (wid >> 1) * 64;
    int wn = (wid & 1) * 64;

    // staging: wave wid owns rows wid*32..wid*32+31 (4 x 1KB instructions).
    // linear LDS slot (row, chunk) sources global chunk (chunk ^ (row&7)).
    int srow = wid * 32 + (lane >> 3);                    // + q*8
    int scol = ((lane & 7) ^ (lane >> 3)) * 8;            // swizzled 16B chunk
    const unsigned short* Asrc = Ab + (size_t)(m0 + srow) * 1728 + scol;

    const unsigned short* Bsrc[4];
#pragma unroll
    for (int q = 0; q < 4; ++q) {
        int v = nloc + srow + q * 8;
        int z = v >> 10, h = (v >> 5) & 31, w = v & 31;
        size_t pidx = (size_t)(z + 1) * PP + (h + 1) * PD + (w + 1);
        Bsrc[q] = y1p + pidx * 64 + scol;
    }

#define STAGE(buf, kt)                                                         \
    {                                                                          \
        int dz = (kt) / 9, rem = (kt) - dz * 9;                                \
        int dy = rem / 3, dx = rem - dy * 3;                                   \
        int toff = ((dz - 1) * PP + (dy - 1) * PD + (dx - 1)) * 64;            \
        _Pragma("unroll")                                                      \
        for (int q = 0; q < 4; ++q) {                                          \
            gl_lds16(Asrc + (size_t)q * 8 * 1728 + (kt) * 64,                  \
                     (char*)sA[buf] + (wid * 4 + q) * 1024);                   \
            gl_lds16(Bsrc[q] + toff,                                           \
                     (char*)sB[buf] + (wid * 4 + q) * 1024);                   \
        }                                                                      \
    }

    STAGE(0, 0);
    __syncthreads();

    for (int kt = 0; kt < 27; ++kt) {
        int cur = kt & 1;
        if (kt + 1 < 27) STAGE(cur ^ 1, kt + 1);
#pragma unroll
        for (int ks = 0; ks < 2; ++ks) {
            bf16x8 a[4], b[4];
#pragma unroll
            for (int i = 0; i < 4; ++i) {
                int ar = wm + i * 16 + (lane & 15);
                int ac = ((ks * 4 + (lane >> 4)) ^ (ar & 7)) * 8;
                a[i] = *(const bf16x8*)(sA[cur] + ar * 64 + ac);
                int br = wn + i * 16 + (lane & 15);
                int bc2 = ((ks * 4 + (lane >> 4)) ^ (br & 7)) * 8;
                b[i] = *(const bf16x8*)(sB[cur] + br * 64 + bc2);
            }
#pragma unroll
            for (int i = 0; i < 4; ++i)
#pragma unroll
                for (int j = 0; j < 4; ++j)
                    acc[i][j] = __builtin_amdgcn_mfma_f32_16x16x32_bf16(a[i], b[j], acc[i][j], 0, 0, 0);
        }
        __syncthreads();
    }
#undef STAGE

    // C/D layout: col = lane&15, row = (lane>>4)*4 + reg
    int colb = nloc + wn + (lane & 15);
#pragma unroll
    for (int i = 0; i < 4; ++i) {
#pragma unroll
        for (int r = 0; r < 4; ++r) {
            int m = m0 + wm + i * 16 + (lane >> 4) * 4 + r;
            float bv = be[m];
#pragma unroll
            for (int j = 0; j < 4; ++j)
                y2[(size_t)m * V + colb + j * 16] = acc[i][j][r] + bv;
        }
    }
}

// ---------------------------------------------------------------------------
// Kernel C: pixel-shuffle + softmax(27) + CARAFE combine, LDS-staged.
// Block = one (d,h) cell-row (1024 blocks, 256 threads).
// ---------------------------------------------------------------------------
__global__ __launch_bounds__(256) void kC(const float* __restrict__ y2,
                                          const float* __restrict__ xp,
                                          float* __restrict__ out) {
    __shared__ float  slog[8][27][32];   // 27.6 KB
    __shared__ float4 sxp[9][32][8];     // 36.9 KB
    int t = threadIdx.x;
    int bid = blockIdx.x;
    int d = bid >> 5, h = bid & 31;
    int g = t >> 5, w = t & 31;

    // phase 1a: logits (coalesced 128B segments)
    int vc = d * 1024 + h * 32 + w;
#pragma unroll
    for (int it = 0; it < 27; ++it)
        slog[g][it][w] = y2[(size_t)(it * 8 + g) * V + vc];

    // phase 1b: xp neighborhood rows (fully coalesced float4)
    {
        int xx = t >> 3, q = t & 7;
#pragma unroll
        for (int zy = 0; zy < 9; ++zy) {
            int zi = zy / 3, yi = zy - zi * 3;
            int zz = min(max(d + zi - 1, 0), 31);
            int yy = min(max(h + yi - 1, 0), 31);
            float4 v4 = *(const float4*)(xp + (size_t)(zz * 1024 + yy * 32 + xx) * 32 + q * 4);
            sxp[zy][xx][q ^ (xx & 7)] = v4;
        }
    }
    __syncthreads();

    // phase 2: softmax over 27 taps for (sub=g, cell w), in place
    {
        float lg[27];
#pragma unroll
        for (int tp = 0; tp < 27; ++tp) lg[tp] = slog[g][tp][w];
        float m = lg[0];
#pragma unroll
        for (int tp = 1; tp < 27; ++tp) m = fmaxf(m, lg[tp]);
        float s = 0.f;
#pragma unroll
        for (int tp = 0; tp < 27; ++tp) { lg[tp] = __expf(lg[tp] - m); s += lg[tp]; }
        float inv = 1.f / s;
#pragma unroll
        for (int tp = 0; tp < 27; ++tp) slog[g][tp][w] = lg[tp] * inv;
    }
    __syncthreads();

    // phase 3: combine
    float acc[8][4] = {};
#pragma unroll
    for (int zy = 0; zy < 9; ++zy) {
#pragma unroll
        for (int dx = 0; dx < 3; ++dx) {
            int tap = zy * 3 + dx;
            int xx = min(max(w + dx - 1, 0), 31);
            float4 xv = sxp[zy][xx][g ^ (xx & 7)];
            float wn[8];
#pragma unroll
            for (int sub = 0; sub < 8; ++sub) wn[sub] = slog[sub][tap][w];
#pragma unroll
            for (int sub = 0; sub < 8; ++sub) {
                acc[sub][0] += wn[sub] * xv.x;
                acc[sub][1] += wn[sub] * xv.y;
                acc[sub][2] += wn[sub] * xv.z;
                acc[sub][3] += wn[sub] * xv.w;
            }
        }
    }

    // epilogue: pair l=0/1 into float2 (fx = 2w, 2w+1)
    int fzb = 2 * d, fyb = 2 * h;
#pragma unroll
    for (int sp = 0; sp < 4; ++sp) {          // sub pair (2sp, 2sp+1), sp = i*2+j
        int i = sp >> 1, j = sp & 1;
        size_t ob = (size_t)(fzb + i) * 4096 + (size_t)(fyb + j) * 64 + 2 * w;
#pragma unroll
        for (int k = 0; k < 4; ++k) {
            float2 v2 = make_float2(acc[2 * sp][k], acc[2 * sp + 1][k]);
            *(float2*)(out + (size_t)(g * 4 + k) * FV + ob) = v2;
        }
    }
}

extern "C" void kernel_launch(void* const* d_in, const int* in_sizes, int n_in,
                              void* d_out, int out_size, void* d_ws, size_t ws_size,
                              hipStream_t stream) {
    const float* x  = (const float*)d_in[0];
    const float* Wc = (const float*)d_in[1];
    const float* bc = (const float*)d_in[2];
    const float* We = (const float*)d_in[3];
    const float* be = (const float*)d_in[4];
    const float* Wp = (const float*)d_in[5];
    float* out = (float*)d_out;

    float* ws = (float*)d_ws;
    float* y2 = ws;                                        // 216*V f32 = 28.3 MB
    float* xp = y2 + (size_t)216 * V;                      // 32*V  f32 =  4 MB
    unsigned short* Ab  = (unsigned short*)(xp + (size_t)32 * V);  // 216*1728 bf16
    unsigned short* y1p = Ab + (size_t)216 * 1728;         // 34^3*64 bf16 = 5 MB

    kP<<<NBA + NBX + NBW, 256, 0, stream>>>(x, Wc, bc, Wp, We, y1p, xp, Ab);
    kG<<<dim3(V / 128, 2), 256, 0, stream>>>(Ab, y1p, be, y2);
    kC<<<1024, 256, 0, stream>>>(y2, xp, out);
}

// Round 6
// 102.256 us; speedup vs baseline: 13.2084x; 1.0032x over previous
//
#include <hip/hip_runtime.h>
#include <hip/hip_bf16.h>

#define V   32768       // 32*32*32 coarse voxels
#define FV  262144      // 64^3 fine voxels
#define PD  34          // padded dim
#define PP  1156        // 34*34
#define NP  39304       // 34^3

#define NBA 154         // y1p role blocks (ceil(NP/256))
#define NBX 128         // xp role blocks  (V/256)
#define NBW 1458        // weight-permute role blocks (216*1728/256)

typedef __attribute__((ext_vector_type(8))) short bf16x8;
typedef __attribute__((ext_vector_type(4))) float f32x4;

__device__ __forceinline__ unsigned short f2bf(float f) {
    __hip_bfloat16 h = __float2bfloat16(f);   // RNE
    return __builtin_bit_cast(unsigned short, h);
}

__device__ __forceinline__ void gl_lds16(const void* g, void* l) {
    __builtin_amdgcn_global_load_lds(
        (const __attribute__((address_space(1))) unsigned int*)g,
        (__attribute__((address_space(3))) unsigned int*)l,
        16, 0, 0);
}

// ---------------------------------------------------------------------------
// Kernel P (fused prep), role by blockIdx.x:
//  [0,NBA):        y1p[p][c] = bf16(bc[c] + Wc.x[v(p)])  over PADDED voxels,
//                  halo rows written as zeros.
//  [NBA,NBA+NBX):  xp[v][oc] = Wp.x[v]                    (f32, voxel-major)
//  [NBA+NBX, ...): Ab[o][tap*64+c] = bf16(We[o][c][tap])  (GEMM A permute)
// ---------------------------------------------------------------------------
__global__ __launch_bounds__(256) void kP(const float* __restrict__ x,
                                          const float* __restrict__ Wc,
                                          const float* __restrict__ bc,
                                          const float* __restrict__ Wp,
                                          const float* __restrict__ We,
                                          unsigned short* __restrict__ y1p,
                                          float* __restrict__ xp,
                                          unsigned short* __restrict__ Ab) {
    __shared__ __align__(16) float sw[64 * 64];
    __shared__ float sbc[64];
    int tid = threadIdx.x;
    int bid = blockIdx.x;

    if (bid < NBA) {
        // ---- y1p role ----
        for (int i = tid; i < 64 * 64; i += 256) sw[i] = Wc[i];
        for (int i = tid; i < 64; i += 256) sbc[i] = bc[i];
        __syncthreads();

        int p = bid * 256 + tid;
        if (p >= NP) return;
        int pz = p / PP, rr = p - pz * PP;
        int py = rr / PD, px = rr - py * PD;
        unsigned short* dst = y1p + (size_t)p * 64;

        if (pz == 0 || pz == 33 || py == 0 || py == 33 || px == 0 || px == 33) {
            uint4 z4 = make_uint4(0, 0, 0, 0);
#pragma unroll
            for (int q = 0; q < 8; ++q) *(uint4*)(dst + q * 8) = z4;
            return;
        }
        int v = (pz - 1) * 1024 + (py - 1) * 32 + (px - 1);
        float xv[64];
#pragma unroll
        for (int c = 0; c < 64; ++c) xv[c] = x[c * V + v];

        unsigned int row[32];
        for (int m = 0; m < 64; m += 2) {
            float a0 = sbc[m], a1 = sbc[m + 1];
#pragma unroll
            for (int c4 = 0; c4 < 16; ++c4) {
                float4 w0 = *(const float4*)(sw + m * 64 + c4 * 4);
                float4 w1 = *(const float4*)(sw + (m + 1) * 64 + c4 * 4);
                a0 += w0.x * xv[c4 * 4] + w0.y * xv[c4 * 4 + 1] +
                      w0.z * xv[c4 * 4 + 2] + w0.w * xv[c4 * 4 + 3];
                a1 += w1.x * xv[c4 * 4] + w1.y * xv[c4 * 4 + 1] +
                      w1.z * xv[c4 * 4 + 2] + w1.w * xv[c4 * 4 + 3];
            }
            row[m >> 1] = (unsigned int)f2bf(a0) | ((unsigned int)f2bf(a1) << 16);
        }
#pragma unroll
        for (int q = 0; q < 8; ++q)
            *(uint4*)(dst + q * 8) =
                make_uint4(row[q * 4], row[q * 4 + 1], row[q * 4 + 2], row[q * 4 + 3]);

    } else if (bid < NBA + NBX) {
        // ---- xp role ----
        for (int i = tid; i < 32 * 64; i += 256) sw[i] = Wp[i];
        __syncthreads();

        int v = (bid - NBA) * 256 + tid;
        float xv[64];
#pragma unroll
        for (int c = 0; c < 64; ++c) xv[c] = x[c * V + v];

        float pacc[32];
        for (int oc = 0; oc < 32; ++oc) {
            float acc = 0.f;
#pragma unroll
            for (int c4 = 0; c4 < 16; ++c4) {
                float4 w0 = *(const float4*)(sw + oc * 64 + c4 * 4);
                acc += w0.x * xv[c4 * 4] + w0.y * xv[c4 * 4 + 1] +
                       w0.z * xv[c4 * 4 + 2] + w0.w * xv[c4 * 4 + 3];
            }
            pacc[oc] = acc;
        }
#pragma unroll
        for (int q = 0; q < 8; ++q)
            *(float4*)(xp + (size_t)v * 32 + q * 4) =
                make_float4(pacc[q * 4], pacc[q * 4 + 1], pacc[q * 4 + 2], pacc[q * 4 + 3]);

    } else {
        // ---- weight permute role ----
        int idx = (bid - NBA - NBX) * 256 + tid;
        int o = idx / 1728, r = idx - o * 1728;
        int tap = r >> 6, c = r & 63;
        Ab[idx] = f2bf(We[(o * 64 + c) * 27 + tap]);
    }
}

// ---------------------------------------------------------------------------
// Kernel G: implicit-GEMM 3x3x3 conv with a static B halo tile.
// N-tile = 4x4x8 voxel patch (128). Halo box 6x6x10 = 360 padded voxels
// staged ONCE (reg-staged, chunk-XOR swizzle q^=(p&7)).  All 27 taps read
// shifted ds_read_b128 from the halo.  Per tap, only A (16 KB, L2-hot) is
// staged, double-buffered via global_load_lds.
// 4 waves (2x2), wave tile 64x64, 16x16x32 bf16 MFMA.
// blockIdx.y: m0 = 0 or 88 (rows 88..127 computed twice, identical values).
// ---------------------------------------------------------------------------
__global__ __launch_bounds__(256) void kG(const unsigned short* __restrict__ Ab,
                                          const unsigned short* __restrict__ y1p,
                                          const float* __restrict__ be,
                                          float* __restrict__ y2) {
    __shared__ unsigned short sA[2][128 * 64];   // 2 x 16 KB, swizzled chunks
    __shared__ unsigned short sH[360 * 64];      // 45 KB halo, swizzled chunks
    int tid = threadIdx.x, lane = tid & 63, wid = tid >> 6;
    int m0 = blockIdx.y ? 88 : 0;
    int bidx = blockIdx.x;
    int bw = bidx & 3, by = (bidx >> 2) & 7, bz = bidx >> 5;

    // ---- A staging (same swizzled-source pattern as before) ----
    int srow = wid * 32 + (lane >> 3);                    // + q*8
    int scol = ((lane & 7) ^ (lane >> 3)) * 8;            // swizzled 16B chunk
    const unsigned short* Asrc = Ab + (size_t)(m0 + srow) * 1728 + scol;

#define STAGE_A(buf, kt)                                                     \
    { _Pragma("unroll")                                                      \
      for (int q = 0; q < 4; ++q)                                            \
          gl_lds16(Asrc + (size_t)q * 8 * 1728 + (kt) * 64,                  \
                   (char*)sA[buf] + (wid * 4 + q) * 1024); }

    STAGE_A(0, 0);

    // ---- B halo staging: 360 voxels x 8 chunks = 2880 uint4 units ----
    for (int it = 0; it < 12; ++it) {
        int u = it * 256 + tid;
        if (u < 2880) {
            int q = u & 7, p = u >> 3;
            int hw = p % 10, t2 = p / 10;
            int hh = t2 % 6, hz = t2 / 6;
            size_t src = ((size_t)(bz * 4 + hz) * PP + (by * 4 + hh) * PD + (bw * 8 + hw)) * 64
                         + q * 8;
            uint4 val = *(const uint4*)(y1p + src);
            *(uint4*)((char*)sH + (p * 8 + (q ^ (p & 7))) * 16) = val;
        }
    }

    // ---- per-lane constants ----
    int wm = (wid >> 1) * 64;
    int wn = (wid & 1) * 64;

    int a_off[4][2];
#pragma unroll
    for (int i = 0; i < 4; ++i)
#pragma unroll
        for (int ks = 0; ks < 2; ++ks) {
            int ar = wm + i * 16 + (lane & 15);
            int c = ks * 4 + (lane >> 4);
            a_off[i][ks] = (ar * 8 + (c ^ (ar & 7))) * 16;   // byte offset
        }

    int p0[4], vv[4];
#pragma unroll
    for (int j = 0; j < 4; ++j) {
        int n = wn + j * 16 + (lane & 15);
        int zi = n >> 5, hi = (n >> 3) & 3, wi = n & 7;
        p0[j] = zi * 60 + hi * 10 + wi;
        vv[j] = (bz * 4 + zi) * 1024 + (by * 4 + hi) * 32 + bw * 8 + wi;
    }

    f32x4 acc[4][4] = {};
    __syncthreads();    // A(0) + halo both resident

    for (int kt = 0; kt < 27; ++kt) {
        int cur = kt & 1;
        if (kt + 1 < 27) STAGE_A(cur ^ 1, kt + 1);
        int dz = kt / 9, rem = kt - dz * 9;
        int dy = rem / 3, dx = rem - dy * 3;
        int pofs = dz * 60 + dy * 10 + dx;
#pragma unroll
        for (int ks = 0; ks < 2; ++ks) {
            bf16x8 a[4], b[4];
#pragma unroll
            for (int i = 0; i < 4; ++i)
                a[i] = *(const bf16x8*)((char*)sA[cur] + a_off[i][ks]);
            int cc = ks * 4 + (lane >> 4);
#pragma unroll
            for (int j = 0; j < 4; ++j) {
                int p = p0[j] + pofs;
                b[j] = *(const bf16x8*)(sH + p * 64 + (cc ^ (p & 7)) * 8);
            }
#pragma unroll
            for (int i = 0; i < 4; ++i)
#pragma unroll
                for (int j = 0; j < 4; ++j)
                    acc[i][j] = __builtin_amdgcn_mfma_f32_16x16x32_bf16(a[i], b[j], acc[i][j], 0, 0, 0);
        }
        __syncthreads();
    }
#undef STAGE_A

    // C/D layout: col = lane&15 (n side), row = (lane>>4)*4 + reg (m side)
#pragma unroll
    for (int i = 0; i < 4; ++i) {
#pragma unroll
        for (int r = 0; r < 4; ++r) {
            int m = m0 + wm + i * 16 + (lane >> 4) * 4 + r;
            float bv = be[m];
#pragma unroll
            for (int j = 0; j < 4; ++j)
                y2[(size_t)m * V + vv[j]] = acc[i][j][r] + bv;
        }
    }
}

// ---------------------------------------------------------------------------
// Kernel C: pixel-shuffle + softmax(27) + CARAFE combine, LDS-staged.
// Block = one (d,h) cell-row (1024 blocks, 256 threads).
// ---------------------------------------------------------------------------
__global__ __launch_bounds__(256) void kC(const float* __restrict__ y2,
                                          const float* __restrict__ xp,
                                          float* __restrict__ out) {
    __shared__ float  slog[8][27][32];   // 27.6 KB
    __shared__ float4 sxp[9][32][8];     // 36.9 KB
    int t = threadIdx.x;
    int bid = blockIdx.x;
    int d = bid >> 5, h = bid & 31;
    int g = t >> 5, w = t & 31;

    // phase 1a: logits (coalesced 128B segments)
    int vc = d * 1024 + h * 32 + w;
#pragma unroll
    for (int it = 0; it < 27; ++it)
        slog[g][it][w] = y2[(size_t)(it * 8 + g) * V + vc];

    // phase 1b: xp neighborhood rows (fully coalesced float4)
    {
        int xx = t >> 3, q = t & 7;
#pragma unroll
        for (int zy = 0; zy < 9; ++zy) {
            int zi = zy / 3, yi = zy - zi * 3;
            int zz = min(max(d + zi - 1, 0), 31);
            int yy = min(max(h + yi - 1, 0), 31);
            float4 v4 = *(const float4*)(xp + (size_t)(zz * 1024 + yy * 32 + xx) * 32 + q * 4);
            sxp[zy][xx][q ^ (xx & 7)] = v4;
        }
    }
    __syncthreads();

    // phase 2: softmax over 27 taps for (sub=g, cell w), in place
    {
        float lg[27];
#pragma unroll
        for (int tp = 0; tp < 27; ++tp) lg[tp] = slog[g][tp][w];
        float m = lg[0];
#pragma unroll
        for (int tp = 1; tp < 27; ++tp) m = fmaxf(m, lg[tp]);
        float s = 0.f;
#pragma unroll
        for (int tp = 0; tp < 27; ++tp) { lg[tp] = __expf(lg[tp] - m); s += lg[tp]; }
        float inv = 1.f / s;
#pragma unroll
        for (int tp = 0; tp < 27; ++tp) slog[g][tp][w] = lg[tp] * inv;
    }
    __syncthreads();

    // phase 3: combine
    float acc[8][4] = {};
#pragma unroll
    for (int zy = 0; zy < 9; ++zy) {
#pragma unroll
        for (int dx = 0; dx < 3; ++dx) {
            int tap = zy * 3 + dx;
            int xx = min(max(w + dx - 1, 0), 31);
            float4 xv = sxp[zy][xx][g ^ (xx & 7)];
            float wn[8];
#pragma unroll
            for (int sub = 0; sub < 8; ++sub) wn[sub] = slog[sub][tap][w];
#pragma unroll
            for (int sub = 0; sub < 8; ++sub) {
                acc[sub][0] += wn[sub] * xv.x;
                acc[sub][1] += wn[sub] * xv.y;
                acc[sub][2] += wn[sub] * xv.z;
                acc[sub][3] += wn[sub] * xv.w;
            }
        }
    }

    // epilogue: pair l=0/1 into float2 (fx = 2w, 2w+1)
    int fzb = 2 * d, fyb = 2 * h;
#pragma unroll
    for (int sp = 0; sp < 4; ++sp) {          // sub pair (2sp, 2sp+1), sp = i*2+j
        int i = sp >> 1, j = sp & 1;
        size_t ob = (size_t)(fzb + i) * 4096 + (size_t)(fyb + j) * 64 + 2 * w;
#pragma unroll
        for (int k = 0; k < 4; ++k) {
            float2 v2 = make_float2(acc[2 * sp][k], acc[2 * sp + 1][k]);
            *(float2*)(out + (size_t)(g * 4 + k) * FV + ob) = v2;
        }
    }
}

extern "C" void kernel_launch(void* const* d_in, const int* in_sizes, int n_in,
                              void* d_out, int out_size, void* d_ws, size_t ws_size,
                              hipStream_t stream) {
    const float* x  = (const float*)d_in[0];
    const float* Wc = (const float*)d_in[1];
    const float* bc = (const float*)d_in[2];
    const float* We = (const float*)d_in[3];
    const float* be = (const float*)d_in[4];
    const float* Wp = (const float*)d_in[5];
    float* out = (float*)d_out;

    float* ws = (float*)d_ws;
    float* y2 = ws;                                        // 216*V f32 = 28.3 MB
    float* xp = y2 + (size_t)216 * V;                      // 32*V  f32 =  4 MB
    unsigned short* Ab  = (unsigned short*)(xp + (size_t)32 * V);  // 216*1728 bf16
    unsigned short* y1p = Ab + (size_t)216 * 1728;         // 34^3*64 bf16 = 5 MB

    kP<<<NBA + NBX + NBW, 256, 0, stream>>>(x, Wc, bc, Wp, We, y1p, xp, Ab);
    kG<<<dim3(256, 2), 256, 0, stream>>>(Ab, y1p, be, y2);
    kC<<<1024, 256, 0, stream>>>(y2, xp, out);
}